// Round 9
// baseline (55.199 us; speedup 1.0000x reference)
//
#include <hip/hip_runtime.h>
#include <math.h>

#define BB 8192
#define DD 4096
#define EE 64

constexpr float NOISE_EPS = 0.01f;
constexpr int BM  = 64;             // rows per block (main GEMM)
constexpr int BK  = 32;             // K per step (one MFMA K)

typedef __attribute__((ext_vector_type(8))) _Float16 f16x8;
typedef __attribute__((ext_vector_type(4))) float    f32x4;

__device__ __forceinline__ void split8(const float4& a, const float4& b,
                                       f16x8& hi, f16x8& mi) {
    float v[8] = {a.x, a.y, a.z, a.w, b.x, b.y, b.z, b.w};
    #pragma unroll
    for (int j = 0; j < 8; ++j) {
        _Float16 h = (_Float16)v[j];          // RN
        hi[j] = h;
        mi[j] = (_Float16)(v[j] - (float)h);
    }
}

__device__ __forceinline__ void gl_lds16(const void* g, void* l) {
    __builtin_amdgcn_global_load_lds(
        (const __attribute__((address_space(1))) unsigned*)g,
        (__attribute__((address_space(3))) unsigned*)l, 16, 0, 0);
}

// ---- pre-pass: pack weights into fp16 hi/mid planes in FRAGMENT order ----
// wpk chunk T (16 KB, T = global k-step): [cb 0..7][plane 0..1][lane 0..63] x 16B
// content(cb,p,lane): 8 fp16, weight row cb*16+(lane&15), k = T*32+(lane>>4)*8..
__global__ __launch_bounds__(256) void wsplit_pack(
    const float* __restrict__ gw, const float* __restrict__ ngw,
    char* __restrict__ wpk)
{
    const int gid = blockIdx.x * 256 + threadIdx.x;   // 65536 threads
    const int r   = gid >> 9;                         // 0..127
    const int kc  = gid & 511;                        // 8-float chunk in row
    const int k0  = kc * 8;
    const float* src = (r < EE) ? gw + (size_t)r * DD + k0
                                : ngw + (size_t)(r - EE) * DD + k0;
    float4 a = *reinterpret_cast<const float4*>(src);
    float4 b = *reinterpret_cast<const float4*>(src + 4);
    f16x8 hi, mi;
    split8(a, b, hi, mi);
    const int T    = k0 >> 5;
    const int kq   = (k0 >> 3) & 3;
    const int cb   = r >> 4;
    const int lane = kq * 16 + (r & 15);
    char* base = wpk + (size_t)T * 16384;
    *reinterpret_cast<f16x8*>(base + ((cb * 2 + 0) * 64 + lane) * 16) = hi;
    *reinterpret_cast<f16x8*>(base + ((cb * 2 + 1) * 64 + lane) * 16) = mi;
}

// ------------------------------- main GEMM --------------------------------
// 8 waves = 2M x 2N sub-tiles (wave owns 32 rows x 32 cols). B-fragments come
// DIRECTLY from the frag-packed global buffer (L2-resident, coalesced 1KB/load)
// -> no w LDS staging, no B LDS reads. x quad-buffered in LDS via
// global_load_lds; one counted vmcnt + one barrier per K-step.
template <int SK>
__global__ __launch_bounds__(512, 4) void gating_main(
    const float* __restrict__ x,
    const char*  __restrict__ wpk,
    float* __restrict__ partial)       // [SK][BB][128]
{
    constexpr int KC  = DD / SK;
    constexpr int NKS = KC / BK;       // even (>= 4)

    __shared__ __align__(1024) char xbuf[4][8192];   // fp32 x tile [64][32], chunk-swizzled

    const int tid  = threadIdx.x;
    const int bid  = blockIdx.x;
    const int sk   = bid & (SK - 1);
    const int row0 = (bid / SK) * BM;
    const int lane = tid & 63;
    const int wv   = tid >> 6;          // 8 waves: 2M x 4N? -> 2M x (wv>>1) cols
    const int m2   = wv & 1;            // 0..1 : rows m2*32 ..
    const int n2   = wv >> 1;           // 0..3 : cols n2*32 ..
    const int l15  = lane & 15;
    const int kq   = lane >> 4;

    // x staging source: thread tid fills LDS byte tid*16; swizzled chunk select
    const int xrow = tid >> 3;          // 0..63
    const int xch  = tid & 7;
    const float* xg = x + (size_t)(row0 + xrow) * DD + sk * KC
                        + ((xch ^ (xrow & 7)) << 2);
    const int ldst = wv * 1024;         // wave-uniform staging dest offset
    char* xls = (char*)&xbuf[0][0];

    // A-frag byte offsets (swizzled read of fp32 x rows), mb = 0,1 ; u = 0,1
    int xoff[2][2];
    #pragma unroll
    for (int mb = 0; mb < 2; ++mb) {
        const int ar = m2 * 32 + mb * 16 + l15;
        #pragma unroll
        for (int u = 0; u < 2; ++u)
            xoff[mb][u] = ar * 128 + (((kq * 2 + u) ^ (ar & 7)) << 4);
    }

    // B direct-from-global: per-lane base + per-(nb,plane) offsets
    const char* wgB = wpk + ((size_t)(sk * NKS) << 14) + lane * 16;
    const int off_h0 = ((n2 * 2 + 0) * 2 + 0) * 1024;
    const int off_m0 = ((n2 * 2 + 0) * 2 + 1) * 1024;
    const int off_h1 = ((n2 * 2 + 1) * 2 + 0) * 1024;
    const int off_m1 = ((n2 * 2 + 1) * 2 + 1) * 1024;

    f32x4 acc00 = {0.f,0.f,0.f,0.f}, acc01 = {0.f,0.f,0.f,0.f};
    f32x4 acc10 = {0.f,0.f,0.f,0.f}, acc11 = {0.f,0.f,0.f,0.f};

    #define LOADB(t, BH0, BM0, BH1, BM1) do {                                  \
        const char* _b = wgB + ((size_t)(t) << 14);                            \
        BH0 = *reinterpret_cast<const f16x8*>(_b + off_h0);                    \
        BM0 = *reinterpret_cast<const f16x8*>(_b + off_m0);                    \
        BH1 = *reinterpret_cast<const f16x8*>(_b + off_h1);                    \
        BM1 = *reinterpret_cast<const f16x8*>(_b + off_m1);                    \
    } while (0)

    #define COMPUTE(t, BH0, BM0, BH1, BM1) do {                                \
        const char* _xb = xls + (((t) & 3) << 13);                             \
        float4 a00 = *reinterpret_cast<const float4*>(_xb + xoff[0][0]);       \
        float4 a01 = *reinterpret_cast<const float4*>(_xb + xoff[0][1]);       \
        float4 a10 = *reinterpret_cast<const float4*>(_xb + xoff[1][0]);       \
        float4 a11 = *reinterpret_cast<const float4*>(_xb + xoff[1][1]);       \
        f16x8 ah0, am0, ah1, am1;                                              \
        split8(a00, a01, ah0, am0);                                            \
        split8(a10, a11, ah1, am1);                                            \
        acc00 = __builtin_amdgcn_mfma_f32_16x16x32_f16(ah0, BH0, acc00, 0,0,0);\
        acc01 = __builtin_amdgcn_mfma_f32_16x16x32_f16(ah0, BH1, acc01, 0,0,0);\
        acc10 = __builtin_amdgcn_mfma_f32_16x16x32_f16(ah1, BH0, acc10, 0,0,0);\
        acc11 = __builtin_amdgcn_mfma_f32_16x16x32_f16(ah1, BH1, acc11, 0,0,0);\
        acc00 = __builtin_amdgcn_mfma_f32_16x16x32_f16(am0, BH0, acc00, 0,0,0);\
        acc01 = __builtin_amdgcn_mfma_f32_16x16x32_f16(am0, BH1, acc01, 0,0,0);\
        acc10 = __builtin_amdgcn_mfma_f32_16x16x32_f16(am1, BH0, acc10, 0,0,0);\
        acc11 = __builtin_amdgcn_mfma_f32_16x16x32_f16(am1, BH1, acc11, 0,0,0);\
        acc00 = __builtin_amdgcn_mfma_f32_16x16x32_f16(ah0, BM0, acc00, 0,0,0);\
        acc01 = __builtin_amdgcn_mfma_f32_16x16x32_f16(ah0, BM1, acc01, 0,0,0);\
        acc10 = __builtin_amdgcn_mfma_f32_16x16x32_f16(ah1, BM0, acc10, 0,0,0);\
        acc11 = __builtin_amdgcn_mfma_f32_16x16x32_f16(ah1, BM1, acc11, 0,0,0);\
    } while (0)

    f16x8 pH0, pM0, pH1, pM1;   // B regs, even tiles
    f16x8 qH0, qM0, qH1, qM1;   // B regs, odd tiles

    // ---- prologue: stage x0..x2, load B(0); drain once ----
    gl_lds16(xg,            xls + ldst);
    gl_lds16(xg + BK,       xls + 8192 + ldst);
    gl_lds16(xg + 2 * BK,   xls + 16384 + ldst);
    LOADB(0, pH0, pM0, pH1, pM1);
    asm volatile("s_waitcnt vmcnt(0)" ::: "memory");
    __builtin_amdgcn_s_barrier();

    // ---- main loop: 2 tiles per trip; 1 vmcnt(5) + 1 barrier per tile ----
    for (int t = 0; t < NKS; t += 2) {
        {   // even tile t (B in p*, load next into q*)
            const int tb = (t + 1 < NKS) ? t + 1 : NKS - 1;
            LOADB(tb, qH0, qM0, qH1, qM1);
            asm volatile("s_waitcnt vmcnt(5)" ::: "memory");
            __builtin_amdgcn_s_barrier();
            const int tx = (t + 3 < NKS) ? t + 3 : NKS - 1;
            gl_lds16(xg + (size_t)tx * BK, xls + (((t + 3) & 3) << 13) + ldst);
            COMPUTE(t, pH0, pM0, pH1, pM1);
        }
        {   // odd tile t+1 (B in q*, load next into p*)
            const int tb = (t + 2 < NKS) ? t + 2 : NKS - 1;
            LOADB(tb, pH0, pM0, pH1, pM1);
            asm volatile("s_waitcnt vmcnt(5)" ::: "memory");
            __builtin_amdgcn_s_barrier();
            const int tx = (t + 4 < NKS) ? t + 4 : NKS - 1;
            gl_lds16(xg + (size_t)tx * BK, xls + (((t + 4) & 3) << 13) + ldst);
            COMPUTE(t + 1, qH0, qM0, qH1, qM1);
        }
    }
    asm volatile("s_waitcnt vmcnt(0)" ::: "memory");   // drain clamped tail

    #undef LOADB
    #undef COMPUTE

    // ---- partial logits out (deterministic, no atomics) ----
    const size_t pbase = ((size_t)sk * BB + row0) * 128;
    #pragma unroll
    for (int j = 0; j < 4; ++j) {
        const int r0 = m2 * 32 + kq * 4 + j;
        const int c0 = n2 * 32 + l15;
        partial[pbase + (size_t)r0 * 128 + c0]             = acc00[j];
        partial[pbase + (size_t)r0 * 128 + c0 + 16]        = acc01[j];
        partial[pbase + (size_t)(r0 + 16) * 128 + c0]      = acc10[j];
        partial[pbase + (size_t)(r0 + 16) * 128 + c0 + 16] = acc11[j];
    }
}

// ------------------------------- epilogue ---------------------------------
template <int SK>
__global__ __launch_bounds__(512) void gating_epi(
    const float* __restrict__ partial,   // [SK][BB][128]
    const float* __restrict__ noise,     // [B, E]
    float* __restrict__ out)             // gates [B,E] then load [B,E]
{
    const int tid  = threadIdx.x;
    const int wv   = tid >> 6;
    const int lane = tid & 63;
    const int l15  = lane & 15;
    const int kq   = lane >> 4;
    const int grow = blockIdx.x * 32 + wv * 4 + kq;
    const int s    = l15;                // experts 4s..4s+3

    const float* pb = partial + (size_t)grow * 128 + 4 * s;
    float4 c4 = {0.f,0.f,0.f,0.f}, n4 = {0.f,0.f,0.f,0.f};
    #pragma unroll
    for (int k = 0; k < SK; ++k) {
        const float* p = pb + (size_t)k * BB * 128;
        float4 a = *reinterpret_cast<const float4*>(p);
        float4 b = *reinterpret_cast<const float4*>(p + 64);
        c4.x += a.x; c4.y += a.y; c4.z += a.z; c4.w += a.w;
        n4.x += b.x; n4.y += b.y; n4.z += b.z; n4.w += b.w;
    }

    float4 nz = *reinterpret_cast<const float4*>(noise + (size_t)grow * EE + 4 * s);

    float cc[4] = {c4.x, c4.y, c4.z, c4.w};
    float nl[4] = {n4.x, n4.y, n4.z, n4.w};
    float m1 = -3.4e38f, m2 = -3.4e38f;
    int   i1 = -1, i2 = -1;
    float cmax = -3.4e38f;
    #pragma unroll
    for (int j = 0; j < 4; ++j) {
        const int e = 4 * s + j;
        float sp  = fmaxf(nl[j], 0.0f) + log1pf(expf(-fabsf(nl[j])));  // softplus
        float nzj = (j == 0) ? nz.x : (j == 1) ? nz.y : (j == 2) ? nz.z : nz.w;
        float vno = fmaf(nzj * sp, NOISE_EPS, cc[j]);
        if (vno > m1)      { m2 = m1; i2 = i1; m1 = vno; i1 = e; }
        else if (vno > m2) { m2 = vno; i2 = e; }
        cmax = fmaxf(cmax, cc[j]);
    }

    // 16-lane reduce: top-2 with (value, lower-index) tiebreak + clean max
    #pragma unroll
    for (int m = 1; m < 16; m <<= 1) {
        float b1 = __shfl_xor(m1, m, 16);
        int  bi1 = __shfl_xor(i1, m, 16);
        float b2 = __shfl_xor(m2, m, 16);
        int  bi2 = __shfl_xor(i2, m, 16);
        cmax = fmaxf(cmax, __shfl_xor(cmax, m, 16));

        bool bwin = (b1 > m1) || (b1 == m1 && bi1 < i1);
        float t1; int ti1; float t2; int ti2;
        if (bwin) {
            t1 = b1; ti1 = bi1;
            bool aw = (m1 > b2) || (m1 == b2 && i1 < bi2);
            t2 = aw ? m1 : b2; ti2 = aw ? i1 : bi2;
        } else {
            t1 = m1; ti1 = i1;
            bool bw = (b1 > m2) || (b1 == m2 && bi1 < i2);
            t2 = bw ? b1 : m2; ti2 = bw ? bi1 : i2;
        }
        m1 = t1; i1 = ti1; m2 = t2; i2 = ti2;
    }

    float tq = expf(m2 - m1);
    float p1 = 1.0f / (1.0f + tq);
    float p2 = tq * p1;

    float e0 = expf(cc[0] - cmax);
    float e1 = expf(cc[1] - cmax);
    float e2 = expf(cc[2] - cmax);
    float e3 = expf(cc[3] - cmax);
    float sum = e0 + e1 + e2 + e3;
    #pragma unroll
    for (int m = 1; m < 16; m <<= 1) sum += __shfl_xor(sum, m, 16);
    float inv = 1.0f / sum;

    const int eb = 4 * s;
    float4 gt;
    gt.x = (eb     == i1) ? p1 : (eb     == i2) ? p2 : 0.0f;
    gt.y = (eb + 1 == i1) ? p1 : (eb + 1 == i2) ? p2 : 0.0f;
    gt.z = (eb + 2 == i1) ? p1 : (eb + 2 == i2) ? p2 : 0.0f;
    gt.w = (eb + 3 == i1) ? p1 : (eb + 3 == i2) ? p2 : 0.0f;
    float4 ld = {e0 * inv, e1 * inv, e2 * inv, e3 * inv};

    *reinterpret_cast<float4*>(out + (size_t)grow * EE + eb) = gt;
    *reinterpret_cast<float4*>(out + (size_t)BB * EE + (size_t)grow * EE + eb) = ld;
}

extern "C" void kernel_launch(void* const* d_in, const int* in_sizes, int n_in,
                              void* d_out, int out_size, void* d_ws, size_t ws_size,
                              hipStream_t stream) {
    const float* x     = (const float*)d_in[0];
    const float* gw    = (const float*)d_in[1];
    const float* ngw   = (const float*)d_in[2];
    const float* noise = (const float*)d_in[3];
    float* out = (float*)d_out;

    char*  wpk     = (char*)d_ws;                                // 2 MB packed w
    float* partial = (float*)(wpk + (size_t)2 * 1024 * 1024);    // SK * 4 MB

    const size_t MB = 1024 * 1024;

    hipLaunchKernelGGL(wsplit_pack, dim3(256), dim3(256), 0, stream, gw, ngw, wpk);

    if (ws_size >= 18 * MB) {
        hipLaunchKernelGGL(gating_main<4>, dim3((BB / BM) * 4), dim3(512), 0, stream,
                           x, wpk, partial);
        hipLaunchKernelGGL(gating_epi<4>, dim3(BB / 32), dim3(512), 0, stream,
                           partial, noise, out);
    } else if (ws_size >= 10 * MB) {
        hipLaunchKernelGGL(gating_main<2>, dim3((BB / BM) * 2), dim3(512), 0, stream,
                           x, wpk, partial);
        hipLaunchKernelGGL(gating_epi<2>, dim3(BB / 32), dim3(512), 0, stream,
                           partial, noise, out);
    } else {
        hipLaunchKernelGGL(gating_main<1>, dim3(BB / BM), dim3(512), 0, stream,
                           x, wpk, partial);
        hipLaunchKernelGGL(gating_epi<1>, dim3(BB / 32), dim3(512), 0, stream,
                           partial, noise, out);
    }
}